// Round 1
// baseline (316.389 us; speedup 1.0000x reference)
//
#include <hip/hip_runtime.h>
#include <hip/hip_bf16.h>

#define NN 50000
#define NE 800000
#define HID 128
#define KDIM 257          // 2*HID + 1
#define KPAD 288          // padded to multiple of 32
#define PITCH1 296        // bf16 elems/row of input tile (148 dwords, %32==20 -> <=2-way banks)
#define PITCH2 152        // bf16 elems/row of x1 tile (76 dwords, %32==12 -> <=2-way banks)
#define MTILE 64          // edges per block

typedef float f32x4 __attribute__((ext_vector_type(4)));
typedef short s16x8 __attribute__((ext_vector_type(8)));

__device__ __forceinline__ unsigned short f2bf(float x) {
    unsigned int u = __float_as_uint(x);
    unsigned int r = (u + 0x7FFFu + ((u >> 16) & 1u)) >> 16;
    return (unsigned short)r;
}

__device__ __forceinline__ float silu_f(float v) {
    return v / (1.f + __expf(-v));
}

// Repack W1 [257,128] f32 -> W1p bf16 [36 kblk][128 n][8 kin] (zero-padded K to 288)
// and W2 [128,128] f32 -> W2p bf16 [16][128][8].
__global__ void prep_weights(const float* __restrict__ W1, const float* __restrict__ W2,
                             unsigned short* __restrict__ W1p, unsigned short* __restrict__ W2p) {
    int idx = blockIdx.x * blockDim.x + threadIdx.x;
    const int n1 = 36 * 128 * 8;
    if (idx < n1) {
        int kblk = idx >> 10;        // /(128*8)
        int rem  = idx & 1023;
        int n    = rem >> 3;
        int kin  = rem & 7;
        int k    = kblk * 8 + kin;
        float v  = (k < KDIM) ? W1[k * HID + n] : 0.f;
        W1p[idx] = f2bf(v);
    } else {
        int j = idx - n1;
        if (j < 16 * 128 * 8) {
            int kblk = j >> 10;
            int rem  = j & 1023;
            int n    = rem >> 3;
            int kin  = rem & 7;
            int k    = kblk * 8 + kin;
            W2p[j] = f2bf(W2[k * HID + n]);
        }
    }
}

__global__ __launch_bounds__(256) void edge_kernel(
        const float* __restrict__ h, const int* __restrict__ edge_index,
        const float* __restrict__ coord_diff, const float* __restrict__ edge_attr,
        const float* __restrict__ edge_mask,
        const unsigned short* __restrict__ W1p, const unsigned short* __restrict__ W2p,
        const float* __restrict__ b1, const float* __restrict__ b2,
        const float* __restrict__ W3, float* __restrict__ agg) {
    __shared__ short s_inp[MTILE * PITCH1];   // 37888 B; x1 tile overlays this after layer 1
    __shared__ float s_phi[MTILE * 4];
    __shared__ int   s_idx[2 * MTILE];        // [m][0]=row, [m][1]=col

    const int tid = threadIdx.x;
    const int e0  = blockIdx.x * MTILE;

    if (tid < 2 * MTILE) {
        int m = tid >> 1, which = tid & 1;
        s_idx[tid] = edge_index[which * NE + e0 + m];
    }
    __syncthreads();

    // ---- stage gathered A tile: [64 edges][h[row](128) | h[col](128) | ea | 0-pad] as bf16
    #pragma unroll
    for (int it = 0; it < 16; ++it) {
        int c      = it * 256 + tid;      // 0..4095
        int row_id = c >> 5;              // 0..127
        int part   = c & 31;              // float4 chunk within the 128-f32 row
        int m      = row_id >> 1;
        int which  = row_id & 1;
        int idx    = s_idx[(m << 1) | which];
        const float4 v = *(const float4*)(h + (size_t)idx * HID + part * 4);
        short4 pk;
        pk.x = (short)f2bf(v.x); pk.y = (short)f2bf(v.y);
        pk.z = (short)f2bf(v.z); pk.w = (short)f2bf(v.w);
        *(short4*)&s_inp[m * PITCH1 + which * HID + part * 4] = pk;
    }
    if (tid < MTILE) {
        int m = tid;
        short4 z; z.x = z.y = z.z = z.w = 0;
        short* p = &s_inp[m * PITCH1 + 256];
        #pragma unroll
        for (int i = 0; i < 40; i += 4) *(short4*)(p + i) = z;   // zero k=256..295
        p[0] = (short)f2bf(edge_attr[e0 + m]);                   // k=256 is edge_attr
    }
    __syncthreads();

    const int lane = tid & 63;
    const int w    = tid >> 6;        // wave id: owns cols [w*32, w*32+32)
    const int q    = lane >> 4;       // quad
    const int c16  = lane & 15;
    const int n0   = w * 32 + c16;

    // ---- layer 1: [64,288] @ [288,128] -> acc (each wave: 4 m-tiles x 2 n-tiles)
    f32x4 acc[4][2];
    #pragma unroll
    for (int mt = 0; mt < 4; ++mt)
        #pragma unroll
        for (int nt = 0; nt < 2; ++nt)
            acc[mt][nt] = f32x4{0.f, 0.f, 0.f, 0.f};

    #pragma unroll
    for (int ks = 0; ks < 9; ++ks) {
        int k0   = ks * 32;
        int kblk = ks * 4 + q;
        s16x8 bfr0 = *(const s16x8*)(W1p + ((size_t)(kblk * HID + n0)) * 8);
        s16x8 bfr1 = *(const s16x8*)(W1p + ((size_t)(kblk * HID + n0 + 16)) * 8);
        #pragma unroll
        for (int mt = 0; mt < 4; ++mt) {
            s16x8 afr = *(const s16x8*)&s_inp[(mt * 16 + c16) * PITCH1 + k0 + q * 8];
            acc[mt][0] = __builtin_amdgcn_mfma_f32_16x16x32_bf16(afr, bfr0, acc[mt][0], 0, 0, 0);
            acc[mt][1] = __builtin_amdgcn_mfma_f32_16x16x32_bf16(afr, bfr1, acc[mt][1], 0, 0, 0);
        }
    }
    __syncthreads();   // everyone done reading s_inp

    // ---- SiLU + write x1 tile (bf16, pitch 152), overlaying s_inp
    {
        float b1v0 = b1[n0], b1v1 = b1[n0 + 16];
        #pragma unroll
        for (int mt = 0; mt < 4; ++mt) {
            #pragma unroll
            for (int r = 0; r < 4; ++r) {
                int m = mt * 16 + q * 4 + r;    // C/D layout: col=lane&15, row=quad*4+reg
                float s0 = silu_f(acc[mt][0][r] + b1v0);
                float s1 = silu_f(acc[mt][1][r] + b1v1);
                s_inp[m * PITCH2 + n0]      = (short)f2bf(s0);
                s_inp[m * PITCH2 + n0 + 16] = (short)f2bf(s1);
            }
        }
    }
    __syncthreads();

    // ---- layer 2: [64,128] @ [128,128]
    f32x4 acc2[4][2];
    #pragma unroll
    for (int mt = 0; mt < 4; ++mt)
        #pragma unroll
        for (int nt = 0; nt < 2; ++nt)
            acc2[mt][nt] = f32x4{0.f, 0.f, 0.f, 0.f};

    #pragma unroll
    for (int ks = 0; ks < 4; ++ks) {
        int k0   = ks * 32;
        int kblk = ks * 4 + q;
        s16x8 bfr0 = *(const s16x8*)(W2p + ((size_t)(kblk * HID + n0)) * 8);
        s16x8 bfr1 = *(const s16x8*)(W2p + ((size_t)(kblk * HID + n0 + 16)) * 8);
        #pragma unroll
        for (int mt = 0; mt < 4; ++mt) {
            s16x8 afr = *(const s16x8*)&s_inp[(mt * 16 + c16) * PITCH2 + k0 + q * 8];
            acc2[mt][0] = __builtin_amdgcn_mfma_f32_16x16x32_bf16(afr, bfr0, acc2[mt][0], 0, 0, 0);
            acc2[mt][1] = __builtin_amdgcn_mfma_f32_16x16x32_bf16(afr, bfr1, acc2[mt][1], 0, 0, 0);
        }
    }

    // ---- layer 3: phi[m] = sum_n silu(x2[m][n] + b2[n]) * W3[n]
    {
        float b2v0 = b2[n0], b2v1 = b2[n0 + 16];
        float w30  = W3[n0], w31  = W3[n0 + 16];
        #pragma unroll
        for (int mt = 0; mt < 4; ++mt) {
            float pr[4];
            #pragma unroll
            for (int r = 0; r < 4; ++r) {
                float s0 = silu_f(acc2[mt][0][r] + b2v0);
                float s1 = silu_f(acc2[mt][1][r] + b2v1);
                pr[r] = s0 * w30 + s1 * w31;
            }
            // reduce over the 16 lanes that share the same rows (same quad)
            #pragma unroll
            for (int off = 8; off >= 1; off >>= 1) {
                #pragma unroll
                for (int r = 0; r < 4; ++r) pr[r] += __shfl_xor(pr[r], off);
            }
            if (c16 == 0) {
                #pragma unroll
                for (int r = 0; r < 4; ++r)
                    s_phi[(mt * 16 + q * 4 + r) * 4 + w] = pr[r];
            }
        }
    }
    __syncthreads();

    // ---- epilogue: trans = coord_diff * phi * edge_mask, atomic scatter-add
    if (tid < MTILE) {
        int e = e0 + tid;
        float phi = s_phi[tid * 4] + s_phi[tid * 4 + 1] + s_phi[tid * 4 + 2] + s_phi[tid * 4 + 3];
        float scale = phi * edge_mask[e];
        int r = s_idx[tid << 1];     // row index = segment id
        float cx = coord_diff[e * 3 + 0];
        float cy = coord_diff[e * 3 + 1];
        float cz = coord_diff[e * 3 + 2];
        atomicAdd(&agg[r * 3 + 0], cx * scale);
        atomicAdd(&agg[r * 3 + 1], cy * scale);
        atomicAdd(&agg[r * 3 + 2], cz * scale);
    }
}

__global__ void finalize_kernel(const float* __restrict__ coord,
                                const float* __restrict__ node_mask,
                                float* __restrict__ out) {
    int i = blockIdx.x * blockDim.x + threadIdx.x;
    if (i < NN) {
        float nm = node_mask[i];
        float a0 = out[i * 3 + 0], a1 = out[i * 3 + 1], a2 = out[i * 3 + 2];
        out[i * 3 + 0] = (coord[i * 3 + 0] + a0 * 0.01f) * nm;
        out[i * 3 + 1] = (coord[i * 3 + 1] + a1 * 0.01f) * nm;
        out[i * 3 + 2] = (coord[i * 3 + 2] + a2 * 0.01f) * nm;
    }
}

extern "C" void kernel_launch(void* const* d_in, const int* in_sizes, int n_in,
                              void* d_out, int out_size, void* d_ws, size_t ws_size,
                              hipStream_t stream) {
    const float* h          = (const float*)d_in[0];
    const float* coord      = (const float*)d_in[1];
    const int*   edge_index = (const int*)d_in[2];
    const float* coord_diff = (const float*)d_in[3];
    // d_in[4] coord_cross: unused by the reference
    const float* edge_attr  = (const float*)d_in[5];
    const float* node_mask  = (const float*)d_in[6];
    const float* edge_mask  = (const float*)d_in[7];
    const float* W1         = (const float*)d_in[8];
    const float* b1         = (const float*)d_in[9];
    const float* W2         = (const float*)d_in[10];
    const float* b2         = (const float*)d_in[11];
    const float* W3         = (const float*)d_in[12];
    float* out = (float*)d_out;

    unsigned short* W1p = (unsigned short*)d_ws;            // 36*128*8 bf16 = 73728 B
    unsigned short* W2p = W1p + 36 * 128 * 8;               // 16*128*8 bf16 = 32768 B

    // agg accumulates directly in d_out (same shape as output)
    hipMemsetAsync(d_out, 0, (size_t)out_size * sizeof(float), stream);

    int prep_threads = 36 * 128 * 8 + 16 * 128 * 8;
    prep_weights<<<(prep_threads + 255) / 256, 256, 0, stream>>>(W1, W2, W1p, W2p);

    edge_kernel<<<NE / MTILE, 256, 0, stream>>>(h, edge_index, coord_diff, edge_attr, edge_mask,
                                                W1p, W2p, b1, b2, W3, out);

    finalize_kernel<<<(NN + 255) / 256, 256, 0, stream>>>(coord, node_mask, out);
}

// Round 2
// 302.618 us; speedup vs baseline: 1.0455x; 1.0455x over previous
//
#include <hip/hip_runtime.h>
#include <hip/hip_bf16.h>

#define NN 50000
#define NE 800000
#define HID 128
#define KDIM 257          // 2*HID + 1
#define KPAD 288          // padded to multiple of 32
#define PITCH1 296        // bf16 elems/row of input tile (148 dwords, %32==20 -> <=2-way banks)
#define PITCH2 152        // bf16 elems/row of x1 tile (76 dwords, %32==12 -> <=2-way banks)
#define MTILE 64          // edges per block

typedef float f32x4 __attribute__((ext_vector_type(4)));
typedef short s16x8 __attribute__((ext_vector_type(8)));

__device__ __forceinline__ unsigned short f2bf(float x) {   // RNE, used in prep only
    unsigned int u = __float_as_uint(x);
    unsigned int r = (u + 0x7FFFu + ((u >> 16) & 1u)) >> 16;
    return (unsigned short)r;
}

// silu without the IEEE divide: v * rcp(1+exp(-v)). v_rcp_f32 ~1ulp, fine for bf16 pipeline.
__device__ __forceinline__ float silu_f(float v) {
    float e = __expf(-v);
    return v * __builtin_amdgcn_rcpf(1.f + e);
}

// One prep kernel: W1 [257,128] -> W1p bf16 [36 kblk][128 n][8 kin] (K zero-padded to 288),
// W2 [128,128] -> W2p bf16 [16][128][8], and (optionally) h f32 -> hb bf16 (RNE).
__global__ void prep_kernel(const float* __restrict__ W1, const float* __restrict__ W2,
                            const float* __restrict__ h,
                            unsigned short* __restrict__ W1p, unsigned short* __restrict__ W2p,
                            unsigned short* __restrict__ hb, int do_h) {
    int idx = blockIdx.x * blockDim.x + threadIdx.x;
    const int n1 = 36 * 128 * 8;
    const int n2 = 16 * 128 * 8;
    if (idx < n1) {
        int kblk = idx >> 10;
        int rem  = idx & 1023;
        int n    = rem >> 3;
        int kin  = rem & 7;
        int k    = kblk * 8 + kin;
        float v  = (k < KDIM) ? W1[k * HID + n] : 0.f;
        W1p[idx] = f2bf(v);
    } else if (idx < n1 + n2) {
        int j    = idx - n1;
        int kblk = j >> 10;
        int rem  = j & 1023;
        int n    = rem >> 3;
        int kin  = rem & 7;
        int k    = kblk * 8 + kin;
        W2p[j] = f2bf(W2[k * HID + n]);
    } else if (do_h) {
        int j = idx - (n1 + n2);            // one float4 -> short4 per thread
        if (j < NN * HID / 4) {
            const float4 v = *(const float4*)(h + (size_t)j * 4);
            short4 pk;
            pk.x = (short)f2bf(v.x); pk.y = (short)f2bf(v.y);
            pk.z = (short)f2bf(v.z); pk.w = (short)f2bf(v.w);
            *(short4*)(hb + (size_t)j * 4) = pk;
        }
    }
}

template <bool USE_HB>
__global__ __launch_bounds__(256) void edge_kernel(
        const unsigned short* __restrict__ hb, const float* __restrict__ h,
        const int* __restrict__ edge_index,
        const float* __restrict__ coord_diff, const float* __restrict__ edge_attr,
        const float* __restrict__ edge_mask,
        const unsigned short* __restrict__ W1p, const unsigned short* __restrict__ W2p,
        const float* __restrict__ b1, const float* __restrict__ b2,
        const float* __restrict__ W3, float* __restrict__ agg) {
    __shared__ short s_inp[MTILE * PITCH1];   // 37888 B; x1 tile overlays this after layer 1
    __shared__ float s_phi[MTILE * 4];
    __shared__ int   s_idx[2 * MTILE];        // [m][0]=row, [m][1]=col

    const int tid = threadIdx.x;
    const int e0  = blockIdx.x * MTILE;

    if (tid < 2 * MTILE) {
        int m = tid >> 1, which = tid & 1;
        s_idx[tid] = edge_index[which * NE + e0 + m];
    }
    __syncthreads();

    // ---- stage gathered A tile: [64 edges][h[row](128) | h[col](128) | ea | 0-pad] as bf16
    if (USE_HB) {
        // pure bf16 copy: 2048 16B chunks, 8 per thread, no conversion math
        #pragma unroll
        for (int it = 0; it < 8; ++it) {
            int c     = it * 256 + tid;      // chunk of 8 bf16
            int m     = c >> 5;
            int sub   = c & 31;
            int which = sub >> 4;
            int part  = sub & 15;
            int idx   = s_idx[(m << 1) | which];
            s16x8 v = *(const s16x8*)(hb + (size_t)idx * HID + part * 8);
            *(s16x8*)&s_inp[m * PITCH1 + which * HID + part * 8] = v;
        }
    } else {
        // f32 gather + truncation-pack (1 v_perm per 2 elems)
        #pragma unroll
        for (int it = 0; it < 16; ++it) {
            int c     = it * 256 + tid;      // float4 chunk
            int m     = c >> 6;
            int sub   = c & 63;
            int which = sub >> 5;
            int part  = sub & 31;
            int idx   = s_idx[(m << 1) | which];
            const float4 v = *(const float4*)(h + (size_t)idx * HID + part * 4);
            uint2 pk;
            pk.x = __builtin_amdgcn_perm(__float_as_uint(v.y), __float_as_uint(v.x), 0x07060302u);
            pk.y = __builtin_amdgcn_perm(__float_as_uint(v.w), __float_as_uint(v.z), 0x07060302u);
            *(uint2*)&s_inp[m * PITCH1 + which * HID + part * 4] = pk;
        }
    }
    if (tid < MTILE) {
        int m = tid;
        short4 z; z.x = z.y = z.z = z.w = 0;
        short* p = &s_inp[m * PITCH1 + 256];
        #pragma unroll
        for (int i = 0; i < 40; i += 4) *(short4*)(p + i) = z;   // zero k=256..295
        p[0] = (short)f2bf(edge_attr[e0 + m]);                   // k=256 is edge_attr
    }
    __syncthreads();

    const int lane = tid & 63;
    const int w    = tid >> 6;        // wave id: owns cols [w*32, w*32+32)
    const int q    = lane >> 4;       // quad
    const int c16  = lane & 15;
    const int n0   = w * 32 + c16;

    // ---- layer 1: [64,288] @ [288,128] -> acc (each wave: 4 m-tiles x 2 n-tiles)
    f32x4 acc[4][2];
    #pragma unroll
    for (int mt = 0; mt < 4; ++mt)
        #pragma unroll
        for (int nt = 0; nt < 2; ++nt)
            acc[mt][nt] = f32x4{0.f, 0.f, 0.f, 0.f};

    #pragma unroll
    for (int ks = 0; ks < 9; ++ks) {
        int k0   = ks * 32;
        int kblk = ks * 4 + q;
        s16x8 bfr0 = *(const s16x8*)(W1p + ((size_t)(kblk * HID + n0)) * 8);
        s16x8 bfr1 = *(const s16x8*)(W1p + ((size_t)(kblk * HID + n0 + 16)) * 8);
        #pragma unroll
        for (int mt = 0; mt < 4; ++mt) {
            s16x8 afr = *(const s16x8*)&s_inp[(mt * 16 + c16) * PITCH1 + k0 + q * 8];
            acc[mt][0] = __builtin_amdgcn_mfma_f32_16x16x32_bf16(afr, bfr0, acc[mt][0], 0, 0, 0);
            acc[mt][1] = __builtin_amdgcn_mfma_f32_16x16x32_bf16(afr, bfr1, acc[mt][1], 0, 0, 0);
        }
    }
    __syncthreads();   // everyone done reading s_inp

    // ---- SiLU + write x1 tile (bf16 via truncation, pitch 152), overlaying s_inp
    {
        float b1v0 = b1[n0], b1v1 = b1[n0 + 16];
        #pragma unroll
        for (int mt = 0; mt < 4; ++mt) {
            #pragma unroll
            for (int r = 0; r < 4; ++r) {
                int m = mt * 16 + q * 4 + r;    // C/D layout: col=lane&15, row=quad*4+reg
                float s0 = silu_f(acc[mt][0][r] + b1v0);
                float s1 = silu_f(acc[mt][1][r] + b1v1);
                s_inp[m * PITCH2 + n0]      = (short)(__float_as_uint(s0) >> 16);
                s_inp[m * PITCH2 + n0 + 16] = (short)(__float_as_uint(s1) >> 16);
            }
        }
    }
    __syncthreads();

    // ---- layer 2: [64,128] @ [128,128]
    f32x4 acc2[4][2];
    #pragma unroll
    for (int mt = 0; mt < 4; ++mt)
        #pragma unroll
        for (int nt = 0; nt < 2; ++nt)
            acc2[mt][nt] = f32x4{0.f, 0.f, 0.f, 0.f};

    #pragma unroll
    for (int ks = 0; ks < 4; ++ks) {
        int k0   = ks * 32;
        int kblk = ks * 4 + q;
        s16x8 bfr0 = *(const s16x8*)(W2p + ((size_t)(kblk * HID + n0)) * 8);
        s16x8 bfr1 = *(const s16x8*)(W2p + ((size_t)(kblk * HID + n0 + 16)) * 8);
        #pragma unroll
        for (int mt = 0; mt < 4; ++mt) {
            s16x8 afr = *(const s16x8*)&s_inp[(mt * 16 + c16) * PITCH2 + k0 + q * 8];
            acc2[mt][0] = __builtin_amdgcn_mfma_f32_16x16x32_bf16(afr, bfr0, acc2[mt][0], 0, 0, 0);
            acc2[mt][1] = __builtin_amdgcn_mfma_f32_16x16x32_bf16(afr, bfr1, acc2[mt][1], 0, 0, 0);
        }
    }

    // ---- layer 3: phi[m] = sum_n silu(x2[m][n] + b2[n]) * W3[n]
    {
        float b2v0 = b2[n0], b2v1 = b2[n0 + 16];
        float w30  = W3[n0], w31  = W3[n0 + 16];
        #pragma unroll
        for (int mt = 0; mt < 4; ++mt) {
            float pr[4];
            #pragma unroll
            for (int r = 0; r < 4; ++r) {
                float s0 = silu_f(acc2[mt][0][r] + b2v0);
                float s1 = silu_f(acc2[mt][1][r] + b2v1);
                pr[r] = s0 * w30 + s1 * w31;
            }
            // reduce over the 16 lanes that share the same rows (same quad)
            #pragma unroll
            for (int off = 8; off >= 1; off >>= 1) {
                #pragma unroll
                for (int r = 0; r < 4; ++r) pr[r] += __shfl_xor(pr[r], off);
            }
            if (c16 == 0) {
                #pragma unroll
                for (int r = 0; r < 4; ++r)
                    s_phi[(mt * 16 + q * 4 + r) * 4 + w] = pr[r];
            }
        }
    }
    __syncthreads();

    // ---- epilogue: trans = coord_diff * phi * edge_mask, atomic scatter-add
    if (tid < MTILE) {
        int e = e0 + tid;
        float phi = s_phi[tid * 4] + s_phi[tid * 4 + 1] + s_phi[tid * 4 + 2] + s_phi[tid * 4 + 3];
        float scale = phi * edge_mask[e];
        int r = s_idx[tid << 1];     // row index = segment id
        float cx = coord_diff[e * 3 + 0];
        float cy = coord_diff[e * 3 + 1];
        float cz = coord_diff[e * 3 + 2];
        atomicAdd(&agg[r * 3 + 0], cx * scale);
        atomicAdd(&agg[r * 3 + 1], cy * scale);
        atomicAdd(&agg[r * 3 + 2], cz * scale);
    }
}

__global__ void finalize_kernel(const float* __restrict__ coord,
                                const float* __restrict__ node_mask,
                                float* __restrict__ out) {
    int i = blockIdx.x * blockDim.x + threadIdx.x;
    if (i < NN) {
        float nm = node_mask[i];
        float a0 = out[i * 3 + 0], a1 = out[i * 3 + 1], a2 = out[i * 3 + 2];
        out[i * 3 + 0] = (coord[i * 3 + 0] + a0 * 0.01f) * nm;
        out[i * 3 + 1] = (coord[i * 3 + 1] + a1 * 0.01f) * nm;
        out[i * 3 + 2] = (coord[i * 3 + 2] + a2 * 0.01f) * nm;
    }
}

extern "C" void kernel_launch(void* const* d_in, const int* in_sizes, int n_in,
                              void* d_out, int out_size, void* d_ws, size_t ws_size,
                              hipStream_t stream) {
    const float* h          = (const float*)d_in[0];
    const float* coord      = (const float*)d_in[1];
    const int*   edge_index = (const int*)d_in[2];
    const float* coord_diff = (const float*)d_in[3];
    // d_in[4] coord_cross: unused by the reference
    const float* edge_attr  = (const float*)d_in[5];
    const float* node_mask  = (const float*)d_in[6];
    const float* edge_mask  = (const float*)d_in[7];
    const float* W1         = (const float*)d_in[8];
    const float* b1         = (const float*)d_in[9];
    const float* W2         = (const float*)d_in[10];
    const float* b2         = (const float*)d_in[11];
    const float* W3         = (const float*)d_in[12];
    float* out = (float*)d_out;

    const int n1 = 36 * 128 * 8;   // W1p shorts
    const int n2 = 16 * 128 * 8;   // W2p shorts
    unsigned short* W1p = (unsigned short*)d_ws;
    unsigned short* W2p = W1p + n1;
    unsigned short* hb  = W2p + n2;
    const size_t need = ((size_t)n1 + n2 + (size_t)NN * HID) * sizeof(unsigned short);
    const bool use_hb = ws_size >= need;

    // agg accumulates directly in d_out (same shape as output)
    hipMemsetAsync(d_out, 0, (size_t)out_size * sizeof(float), stream);

    int prep_items = n1 + n2 + (use_hb ? NN * HID / 4 : 0);
    prep_kernel<<<(prep_items + 255) / 256, 256, 0, stream>>>(W1, W2, h, W1p, W2p, hb,
                                                              use_hb ? 1 : 0);

    if (use_hb) {
        edge_kernel<true><<<NE / MTILE, 256, 0, stream>>>(hb, h, edge_index, coord_diff,
                                                          edge_attr, edge_mask,
                                                          W1p, W2p, b1, b2, W3, out);
    } else {
        edge_kernel<false><<<NE / MTILE, 256, 0, stream>>>(hb, h, edge_index, coord_diff,
                                                           edge_attr, edge_mask,
                                                           W1p, W2p, b1, b2, W3, out);
    }

    finalize_kernel<<<(NN + 255) / 256, 256, 0, stream>>>(coord, node_mask, out);
}